// Round 7
// baseline (72.684 us; speedup 1.0000x reference)
//
#include <hip/hip_runtime.h>
#include <math.h>
#include <stdint.h>

constexpr int Hn = 512, Wn = 512, Bn = 16;
constexpr int GX = 2, GY = 64;          // block = 256 cols x 8 core rows, 4 waves
constexpr int NBLK = GX * GY * Bn;      // 2048 blocks
#define NACC 11
constexpr int REP = 64, PAD = 16;       // 64 replica accumulator rows, 64 B apart
constexpr int NG = 8;                   // level-1 counter groups (64B-padded)
constexpr int GQ = NBLK / NG;           // 256 blocks per group
constexpr float NTOT = 16.f * 512.f * 512.f;

// acc slots: 0 bce, 1 sum_d, 2 sum_t, 3 sum_dt, 4..6 cnt(3,5,7),
//            7..9 bce*mask(3,5,7), 10 detail

__device__ __forceinline__ uint32_t bits4(float4 v) {
    return (uint32_t)(v.x > 0.5f) | ((uint32_t)(v.y > 0.5f) << 1) |
           ((uint32_t)(v.z > 0.5f) << 2) | ((uint32_t)(v.w > 0.5f) << 3);
}
__device__ __forceinline__ float sigm(float x) {
    const float z = __expf(-fabsf(x));
    const float r = __builtin_amdgcn_rcpf(1.f + z);
    return (x >= 0.f) ? r : 1.f - r;
}
__device__ __forceinline__ void pxd(float x, float tf, float& d) {
    const float z = __expf(-fabsf(x));
    const float r = __builtin_amdgcn_rcpf(1.f + z);
    d = ((x >= 0.f) ? r : 1.f - r) - tf;
}
__device__ __forceinline__ void pxb(float x, float tf, float& d, float& b) {
    const float z = __expf(-fabsf(x));
    const float r = __builtin_amdgcn_rcpf(1.f + z);
    d = ((x >= 0.f) ? r : 1.f - r) - tf;
    b = fmaxf((1.f - 2.f * tf) * x, 0.f) + __logf(1.f + z);
}
// horizontal dilate cascade on a 12-bit window word
__device__ __forceinline__ void casc(uint32_t w, uint32_t& p) {
    const uint32_t w1 = w  | (w  << 1) | (w  >> 1);
    const uint32_t w2 = w1 | (w1 << 1) | (w1 >> 1);
    const uint32_t w3 = w2 | (w2 << 1) | (w2 >> 1);
    p = ((w1 >> 4) & 0xFu) | (((w2 >> 4) & 0xFu) << 4) | (((w3 >> 4) & 0xFu) << 8);
}

__global__ __launch_bounds__(256) void crack_main(
    const float* __restrict__ logits, const float* __restrict__ target,
    float* __restrict__ g_part, unsigned int* __restrict__ g_cnt1,
    unsigned int* __restrict__ g_cnt2, float* __restrict__ out)
{
    __shared__ float s_red[4][NACC];
    __shared__ float s_sum[NACC];
    __shared__ unsigned int s_last;

    const int tid = threadIdx.x, lane = tid & 63;
    const int wid = __builtin_amdgcn_readfirstlane(tid >> 6);   // 0..3
    const int x0 = blockIdx.x * 256;
    const int y0 = blockIdx.y * 8 + wid * 2;      // wave owns rows y0, y0+1
    const int gx = x0 + 4 * lane;
    const size_t base = (size_t)blockIdx.z * (size_t)(Hn * Wn);
    const bool leftE = (x0 == 0), rightE = (x0 + 256 >= Wn);
    const int bid = (blockIdx.z * GY + blockIdx.y) * GX + blockIdx.x;

    uint32_t validm = 0xFFFu;                     // valid cols for erosion compl.
    if (leftE && lane == 0)   validm = 0xFF0u;
    if (rightE && lane == 63) validm = 0x0FFu;

    // ---- strip-edge target bits: lanes 0..7 left col-block, 32..39 right ----
    uint32_t eb = 0u;
    {
        const int q = lane & 31, side = lane >> 5;
        const int gy = y0 - 3 + q;
        if (q < 8 && (unsigned)gy < (unsigned)Hn) {
            if (side == 0 && !leftE)
                eb = bits4(*(const float4*)(target + base + (size_t)gy * Wn + (x0 - 4)));
            if (side == 1 && !rightE)
                eb = bits4(*(const float4*)(target + base + (size_t)gy * Wn + (x0 + 256)));
        }
    }
    // ---- edge d values for Laplacian: lanes 0,1 col x0-1; lanes 32,33 col x0+256 ----
    float ed = 0.f;
    {
        const int q = lane & 31, side = lane >> 5;
        const int gy = y0 + q;
        if (q < 2) {
            if (side == 0 && !leftE) {
                const float xl = logits[base + (size_t)gy * Wn + (x0 - 1)];
                const float tl = target[base + (size_t)gy * Wn + (x0 - 1)];
                ed = sigm(xl) - ((tl > 0.5f) ? 1.f : 0.f);
            }
            if (side == 1 && !rightE) {
                const float xr = logits[base + (size_t)gy * Wn + (x0 + 256)];
                const float tr = target[base + (size_t)gy * Wn + (x0 + 256)];
                ed = sigm(xr) - ((tr > 0.5f) ? 1.f : 0.f);
            }
        }
    }

    // ---- morphology: 8 rows y0-3 .. y0+4, packed po|pu per row ----
    uint32_t pm[8];
    uint32_t tbits = 0u;                          // t bits for rows y0-1..y0+2
#pragma unroll
    for (int r = 0; r < 8; ++r) {
        const int gy = y0 - 3 + r;
        const bool rowv = ((unsigned)gy < (unsigned)Hn);
        uint32_t m = 0u;
        if (rowv)
            m = bits4(*(const float4*)(target + base + (size_t)gy * Wn + gx));
        if (r >= 2 && r <= 5) tbits |= m << ((r - 2) * 4);
        uint32_t ml = __shfl_up(m, 1);
        uint32_t mr = __shfl_down(m, 1);
        const uint32_t el = __shfl(eb, r);
        const uint32_t er = __shfl(eb, 32 + r);
        if (lane == 0)  ml = el;
        if (lane == 63) mr = er;
        uint32_t w = 0u, wc = 0u;
        if (rowv) { w = ml | (m << 4) | (mr << 8); wc = (~w) & validm; }
        uint32_t po, pu;
        casc(w, po); casc(wc, pu);
        pm[r] = po | (pu << 12);
    }

    // ---- d field (4 rows y0-1..y0+2) + bce/elementwise on core rows ----
    float4 dm1 = make_float4(0.f, 0.f, 0.f, 0.f);
    float4 dp2 = make_float4(0.f, 0.f, 0.f, 0.f);
    float4 d0, d1, b0, b1;
    float sbce, sd, sdt, stt;
    {
        const int gym = y0 - 1;
        if (gym >= 0) {
            const float4 x = *(const float4*)(logits + base + (size_t)gym * Wn + gx);
            const uint32_t mr = tbits & 0xFu;
            pxd(x.x, (float)(mr & 1u), dm1.x);
            pxd(x.y, (float)((mr >> 1) & 1u), dm1.y);
            pxd(x.z, (float)((mr >> 2) & 1u), dm1.z);
            pxd(x.w, (float)((mr >> 3) & 1u), dm1.w);
        }
        {
            const float4 x = *(const float4*)(logits + base + (size_t)y0 * Wn + gx);
            const uint32_t mr = (tbits >> 4) & 0xFu;
            const float t0 = (float)(mr & 1u), t1 = (float)((mr >> 1) & 1u);
            const float t2 = (float)((mr >> 2) & 1u), t3 = (float)((mr >> 3) & 1u);
            pxb(x.x, t0, d0.x, b0.x); pxb(x.y, t1, d0.y, b0.y);
            pxb(x.z, t2, d0.z, b0.z); pxb(x.w, t3, d0.w, b0.w);
            sbce = b0.x + b0.y + b0.z + b0.w;
            sd   = d0.x + d0.y + d0.z + d0.w;
            sdt  = d0.x * t0 + d0.y * t1 + d0.z * t2 + d0.w * t3;
            stt  = t0 + t1 + t2 + t3;
        }
        {
            const float4 x = *(const float4*)(logits + base + (size_t)(y0 + 1) * Wn + gx);
            const uint32_t mr = (tbits >> 8) & 0xFu;
            const float t0 = (float)(mr & 1u), t1 = (float)((mr >> 1) & 1u);
            const float t2 = (float)((mr >> 2) & 1u), t3 = (float)((mr >> 3) & 1u);
            pxb(x.x, t0, d1.x, b1.x); pxb(x.y, t1, d1.y, b1.y);
            pxb(x.z, t2, d1.z, b1.z); pxb(x.w, t3, d1.w, b1.w);
            sbce += b1.x + b1.y + b1.z + b1.w;
            sd   += d1.x + d1.y + d1.z + d1.w;
            sdt  += d1.x * t0 + d1.y * t1 + d1.z * t2 + d1.w * t3;
            stt  += t0 + t1 + t2 + t3;
        }
        const int gyp = y0 + 2;
        if (gyp < Hn) {
            const float4 x = *(const float4*)(logits + base + (size_t)gyp * Wn + gx);
            const uint32_t mr = (tbits >> 12) & 0xFu;
            pxd(x.x, (float)(mr & 1u), dp2.x);
            pxd(x.y, (float)((mr >> 1) & 1u), dp2.y);
            pxd(x.z, (float)((mr >> 2) & 1u), dp2.z);
            pxd(x.w, (float)((mr >> 3) & 1u), dp2.w);
        }
    }

    // ---- boundary combine + Laplacian for the 2 core rows ----
    float sb1 = 0.f, sb2 = 0.f, sb3 = 0.f, sdet = 0.f;
    int c1 = 0, c2 = 0, c3 = 0;
#pragma unroll
    for (int k = 0; k < 2; ++k) {
        const uint32_t o3 = pm[k + 2] | pm[k + 3] | pm[k + 4];
        const uint32_t o5 = o3 | pm[k + 1] | pm[k + 5];
        const uint32_t o7 = o5 | pm[k] | pm[k + 6];
        const uint32_t vo = (o3 & 0xFu) | (o5 & 0xF0u) | (o7 & 0xF00u);
        const uint32_t vu = ((o3 >> 12) & 0xFu) | ((o5 >> 12) & 0xF0u) |
                            ((o7 >> 12) & 0xF00u);
        const uint32_t b = vo & vu;
        c1 += __popc(b & 0xFu);
        c2 += __popc(b & 0xF0u);
        c3 += __popc(b & 0xF00u);
        const float4 bc = (k == 0) ? b0 : b1;
        sb1 += (((b >> 0) & 1) ? bc.x : 0.f) + (((b >> 1) & 1) ? bc.y : 0.f) +
               (((b >> 2) & 1) ? bc.z : 0.f) + (((b >> 3) & 1) ? bc.w : 0.f);
        sb2 += (((b >> 4) & 1) ? bc.x : 0.f) + (((b >> 5) & 1) ? bc.y : 0.f) +
               (((b >> 6) & 1) ? bc.z : 0.f) + (((b >> 7) & 1) ? bc.w : 0.f);
        sb3 += (((b >> 8) & 1) ? bc.x : 0.f) + (((b >> 9) & 1) ? bc.y : 0.f) +
               (((b >> 10) & 1) ? bc.z : 0.f) + (((b >> 11) & 1) ? bc.w : 0.f);

        const float4 ce = (k == 0) ? d0 : d1;
        const float4 up = (k == 0) ? dm1 : d0;
        const float4 dn = (k == 0) ? d1 : dp2;
        float left = __shfl_up(ce.w, 1);
        { const float el = __shfl(ed, k); if (lane == 0) left = el; }
        float right = __shfl_down(ce.x, 1);
        { const float er = __shfl(ed, 32 + k); if (lane == 63) right = er; }
        sdet += fabsf(left + ce.y + up.x + dn.x - 4.f * ce.x);
        sdet += fabsf(ce.x + ce.z + up.y + dn.y - 4.f * ce.y);
        sdet += fabsf(ce.y + ce.w + up.z + dn.z - 4.f * ce.z);
        sdet += fabsf(ce.z + right + up.w + dn.w - 4.f * ce.w);
    }

    // ---- reduction: wave shuffle -> LDS -> replicated atomics + counter tree ----
    float acc[NACC];
    acc[0] = sbce; acc[1] = sd; acc[2] = stt; acc[3] = sdt;
    acc[4] = (float)c1; acc[5] = (float)c2; acc[6] = (float)c3;
    acc[7] = sb1; acc[8] = sb2; acc[9] = sb3; acc[10] = sdet;
#pragma unroll
    for (int i = 0; i < NACC; ++i) {
        float v = acc[i];
#pragma unroll
        for (int off = 32; off; off >>= 1) v += __shfl_xor(v, off);
        acc[i] = v;
    }
    if (lane == 0) {
#pragma unroll
        for (int i = 0; i < NACC; ++i) s_red[wid][i] = acc[i];
    }
    __syncthreads();
    if (tid < NACC) {
        const float v = s_red[0][tid] + s_red[1][tid] + s_red[2][tid] + s_red[3][tid];
        atomicAdd(&g_part[(size_t)(bid & (REP - 1)) * PAD + tid], v);
    }
    if (tid == 0) {
        __threadfence();                 // drain wave-0's data atomics device-wide
        unsigned int last = 0u;
        if (atomicAdd(&g_cnt1[(bid & (NG - 1)) * 16], 1u) == (unsigned int)(GQ - 1)) {
            if (atomicAdd(g_cnt2, 1u) == (unsigned int)(NG - 1)) last = 1u;
        }
        s_last = last;
    }
    __syncthreads();

    // ---- last block: coherent read of replicas + finalize ----
    if (s_last) {
        if (tid < NACC) s_sum[tid] = 0.f;
        __syncthreads();
        const int slot = tid & 15;
#pragma unroll
        for (int rr = 0; rr < REP; rr += 16) {
            const int rep = rr + (tid >> 4);
            if (slot < NACC) {
                const float v = atomicAdd(&g_part[(size_t)rep * PAD + slot], 0.f);
                atomicAdd(&s_sum[slot], v);
            }
        }
        __syncthreads();
        if (tid == 0) {
            float t[NACC];
#pragma unroll
            for (int i = 0; i < NACC; ++i) t[i] = s_sum[i];
            const float bce   = t[0] / NTOT;
            const float st    = t[2];
            const float sp    = t[1] + t[2];
            const float inter = t[3] + t[2];
            const float dice = 1.f - (2.f * inter + 1.f) / (sp + st + 1.f);
            const float fp = sp - inter, fn = st - inter;
            const float tvi = (inter + 1.f) / (inter + 0.6f * fp + 0.4f * fn + 1.f);
            const float tversky = powf(fmaxf(1.f - tvi, 0.f), 0.75f);
            float tb = 0.f, ns = 0.f;
            for (int i = 0; i < 3; ++i) {
                const float cnt = t[4 + i], sb = t[7 + i];
                if (cnt >= 1.f) { tb += sb / cnt; ns += 1.f; }
            }
            const float boundary = (ns > 0.f) ? tb / ns : 0.f;
            const float detail = t[10] / NTOT;
            out[0] = bce + dice + 0.5f * tversky + 0.5f * boundary + 0.3f * detail;
        }
    }
}

extern "C" void kernel_launch(void* const* d_in, const int* in_sizes, int n_in,
                              void* d_out, int out_size, void* d_ws, size_t ws_size,
                              hipStream_t stream) {
    const float* logits = (const float*)d_in[0];
    const float* target = (const float*)d_in[1];
    float* g_part = (float*)d_ws;                                   // REP*PAD floats (4 KiB)
    unsigned int* g_cnt1 = (unsigned int*)((char*)d_ws + REP * PAD * sizeof(float));
    unsigned int* g_cnt2 = (unsigned int*)((char*)d_ws + REP * PAD * sizeof(float) + NG * 64);

    hipMemsetAsync(d_ws, 0, REP * PAD * sizeof(float) + NG * 64 + 64, stream);
    dim3 grid(GX, GY, Bn);
    crack_main<<<grid, dim3(256), 0, stream>>>(logits, target, g_part, g_cnt1,
                                               g_cnt2, (float*)d_out);
}

// Round 8
// 34.253 us; speedup vs baseline: 2.1220x; 2.1220x over previous
//
#include <hip/hip_runtime.h>
#include <math.h>
#include <stdint.h>

constexpr int Hn = 512, Wn = 512, Bn = 16;
constexpr int GX = 2, GY = 64;       // block = 256 cols x 8 core rows, 4 waves
constexpr int NBLK = GX * GY * Bn;   // 2048 blocks
#define NACC 11
constexpr float NTOT = 16.f * 512.f * 512.f;

// partials (transposed [i][blk]): 0 bce, 1 sum_d, 2 sum_t, 3 sum_dt,
//   4..6 cnt(3,5,7), 7..9 bce*mask(3,5,7), 10 detail

__device__ __forceinline__ uint32_t bits4(float4 v) {
    return (uint32_t)(v.x > 0.5f) | ((uint32_t)(v.y > 0.5f) << 1) |
           ((uint32_t)(v.z > 0.5f) << 2) | ((uint32_t)(v.w > 0.5f) << 3);
}
__device__ __forceinline__ float sigm(float x) {
    const float z = __expf(-fabsf(x));
    const float r = __builtin_amdgcn_rcpf(1.f + z);
    return (x >= 0.f) ? r : 1.f - r;
}
__device__ __forceinline__ void pxd(float x, float tf, float& d) {
    const float z = __expf(-fabsf(x));
    const float r = __builtin_amdgcn_rcpf(1.f + z);
    d = ((x >= 0.f) ? r : 1.f - r) - tf;
}
__device__ __forceinline__ void pxb(float x, float tf, float& d, float& b) {
    const float z = __expf(-fabsf(x));
    const float r = __builtin_amdgcn_rcpf(1.f + z);
    d = ((x >= 0.f) ? r : 1.f - r) - tf;
    b = fmaxf((1.f - 2.f * tf) * x, 0.f) + __logf(1.f + z);
}

__global__ __launch_bounds__(256, 8) void crack_main(
    const float* __restrict__ logits, const float* __restrict__ target,
    float* __restrict__ partials)
{
    __shared__ uint32_t s_pm[14][64];   // po[0:12) | pu[12:24) per morpho row
    __shared__ float s_d[10][256];      // d = sigmoid(x)-t, rows y0-1 .. y0+8
    __shared__ float s_dl[8], s_dr[8];  // edge d cols (x0-1 / x0+256), core rows
    __shared__ float s_red[4][NACC];

    const int tid = threadIdx.x, lane = tid & 63;
    const int wid = __builtin_amdgcn_readfirstlane(tid >> 6);   // 0..3
    const int x0 = blockIdx.x * 256, y0 = blockIdx.y * 8;
    const size_t base = (size_t)blockIdx.z * (size_t)(Hn * Wn);
    const bool leftE = (x0 == 0), rightE = (x0 + 256 >= Wn);
    const int gx = x0 + 4 * lane;

    uint32_t validm = 0xFFFu;                    // valid cols for erosion compl.
    if (leftE && lane == 0)   validm = 0xFF0u;
    if (rightE && lane == 63) validm = 0x0FFu;

    // ---- phase A: horizontal morphology, 14 rows (y0-3 .. y0+10) ----
#pragma unroll
    for (int k = 0; k < 4; ++k) {
        const int r = wid + 4 * k;               // wave-uniform
        if (r < 14) {
            const int gy = y0 - 3 + r;
            uint32_t w = 0u, wc = 0u;
            if ((unsigned)gy < (unsigned)Hn) {
                const float* trow = target + base + (size_t)gy * Wn;
                const uint32_t m = bits4(*(const float4*)(trow + gx));
                uint32_t lw = 0u, rw = 0u;
                if (gx >= 4)      lw = bits4(*(const float4*)(trow + gx - 4));
                if (gx + 8 <= Wn) rw = bits4(*(const float4*)(trow + gx + 4));
                w = lw | (m << 4) | (rw << 8);   // bit b = col gx-4+b
                wc = (~w) & validm;
            }
            const uint32_t w1 = w  | (w  << 1) | (w  >> 1);
            const uint32_t w2 = w1 | (w1 << 1) | (w1 >> 1);
            const uint32_t w3 = w2 | (w2 << 1) | (w2 >> 1);
            const uint32_t u1 = wc | (wc << 1) | (wc >> 1);
            const uint32_t u2 = u1 | (u1 << 1) | (u1 >> 1);
            const uint32_t u3 = u2 | (u2 << 1) | (u2 >> 1);
            const uint32_t po = ((w1 >> 4) & 0xFu) | (((w2 >> 4) & 0xFu) << 4) |
                                (((w3 >> 4) & 0xFu) << 8);
            const uint32_t pu = ((u1 >> 4) & 0xFu) | (((u2 >> 4) & 0xFu) << 4) |
                                (((u3 >> 4) & 0xFu) << 8);
            s_pm[r][lane] = po | (pu << 12);
        }
    }

    // ---- phase B: d rows j = wid+4k (gy = y0-1+j), bce only on core rows ----
    float4 d4[3], bce4[3];
    float sbce = 0.f, sd = 0.f, sdt = 0.f, stt = 0.f;
#pragma unroll
    for (int k = 0; k < 3; ++k) {
        const int j = wid + 4 * k;
        d4[k] = make_float4(0.f, 0.f, 0.f, 0.f);
        bce4[k] = make_float4(0.f, 0.f, 0.f, 0.f);
        if (j < 10) {
            const int gy = y0 - 1 + j;
            if ((unsigned)gy < (unsigned)Hn) {
                const float4 x = *(const float4*)(logits + base + (size_t)gy * Wn + gx);
                const float4 t = *(const float4*)(target + base + (size_t)gy * Wn + gx);
                if (j >= 1 && j <= 8) {          // core row: d + bce + sums
                    float4 d, bc;
                    pxb(x.x, t.x, d.x, bc.x); pxb(x.y, t.y, d.y, bc.y);
                    pxb(x.z, t.z, d.z, bc.z); pxb(x.w, t.w, d.w, bc.w);
                    d4[k] = d; bce4[k] = bc;
                    sbce += bc.x + bc.y + bc.z + bc.w;
                    sd   += d.x + d.y + d.z + d.w;
                    sdt  += d.x * t.x + d.y * t.y + d.z * t.z + d.w * t.w;
                    stt  += t.x + t.y + t.z + t.w;
                } else {                         // halo row: d only
                    float4 d;
                    pxd(x.x, t.x, d.x); pxd(x.y, t.y, d.y);
                    pxd(x.z, t.z, d.z); pxd(x.w, t.w, d.w);
                    d4[k] = d;
                }
            }
            *(float4*)&s_d[j][4 * lane] = d4[k];
        }
    }
    // edge d columns for the Laplacian (8 core rows), by wave 3
    if (wid == 3) {
        if (lane < 8) {
            float v = 0.f;
            if (!leftE) {
                const int gy = y0 + lane;
                const float xl = logits[base + (size_t)gy * Wn + (x0 - 1)];
                const float tl = target[base + (size_t)gy * Wn + (x0 - 1)];
                v = sigm(xl) - ((tl > 0.5f) ? 1.f : 0.f);
            }
            s_dl[lane] = v;
        } else if (lane >= 32 && lane < 40) {
            float v = 0.f;
            if (!rightE) {
                const int gy = y0 + (lane - 32);
                const float xr = logits[base + (size_t)gy * Wn + (x0 + 256)];
                const float tr = target[base + (size_t)gy * Wn + (x0 + 256)];
                v = sigm(xr) - ((tr > 0.5f) ? 1.f : 0.f);
            }
            s_dr[lane - 32] = v;
        }
    }

    __syncthreads();

    // ---- phase C: vertical combine + Laplacian on core rows j = wid+4k ----
    float sb1 = 0.f, sb2 = 0.f, sb3 = 0.f, sdet = 0.f;
    int c1 = 0, c2 = 0, c3 = 0;
#pragma unroll
    for (int k = 0; k < 3; ++k) {
        const int j = wid + 4 * k;
        if (j >= 1 && j <= 8) {
            const uint32_t q0 = s_pm[j - 1][lane], q1 = s_pm[j][lane],
                           q2 = s_pm[j + 1][lane], q3 = s_pm[j + 2][lane],
                           q4 = s_pm[j + 3][lane], q5 = s_pm[j + 4][lane],
                           q6 = s_pm[j + 5][lane];
            const uint32_t o3 = q2 | q3 | q4;
            const uint32_t o5 = o3 | q1 | q5;
            const uint32_t o7 = o5 | q0 | q6;
            const uint32_t vo = (o3 & 0xFu) | (o5 & 0xF0u) | (o7 & 0xF00u);
            const uint32_t vu = ((o3 >> 12) & 0xFu) | ((o5 >> 12) & 0xF0u) |
                                ((o7 >> 12) & 0xF00u);
            const uint32_t b = vo & vu;          // [0:4) r1, [4:8) r2, [8:12) r3
            c1 += __popc(b & 0xFu);
            c2 += __popc(b & 0xF0u);
            c3 += __popc(b & 0xF00u);
            const float4 bc = bce4[k];
            sb1 += (((b >> 0) & 1) ? bc.x : 0.f) + (((b >> 1) & 1) ? bc.y : 0.f) +
                   (((b >> 2) & 1) ? bc.z : 0.f) + (((b >> 3) & 1) ? bc.w : 0.f);
            sb2 += (((b >> 4) & 1) ? bc.x : 0.f) + (((b >> 5) & 1) ? bc.y : 0.f) +
                   (((b >> 6) & 1) ? bc.z : 0.f) + (((b >> 7) & 1) ? bc.w : 0.f);
            sb3 += (((b >> 8) & 1) ? bc.x : 0.f) + (((b >> 9) & 1) ? bc.y : 0.f) +
                   (((b >> 10) & 1) ? bc.z : 0.f) + (((b >> 11) & 1) ? bc.w : 0.f);

            const float4 dc = d4[k];
            const float4 du = *(const float4*)&s_d[j - 1][4 * lane];
            const float4 dd = *(const float4*)&s_d[j + 1][4 * lane];
            float left = __shfl_up(dc.w, 1);
            { const float el = s_dl[j - 1]; if (lane == 0)  left = el; }
            float right = __shfl_down(dc.x, 1);
            { const float er = s_dr[j - 1]; if (lane == 63) right = er; }
            sdet += fabsf(left + dc.y + du.x + dd.x - 4.f * dc.x);
            sdet += fabsf(dc.x + dc.z + du.y + dd.y - 4.f * dc.y);
            sdet += fabsf(dc.y + dc.w + du.z + dd.z - 4.f * dc.z);
            sdet += fabsf(dc.z + right + du.w + dd.w - 4.f * dc.w);
        }
    }

    // ---- block reduction -> partials write (no atomics, no fences) ----
    float acc[NACC];
    acc[0] = sbce; acc[1] = sd; acc[2] = stt; acc[3] = sdt;
    acc[4] = (float)c1; acc[5] = (float)c2; acc[6] = (float)c3;
    acc[7] = sb1; acc[8] = sb2; acc[9] = sb3; acc[10] = sdet;
#pragma unroll
    for (int i = 0; i < NACC; ++i) {
        float v = acc[i];
#pragma unroll
        for (int off = 32; off; off >>= 1) v += __shfl_xor(v, off);
        acc[i] = v;
    }
    if (lane == 0) {
#pragma unroll
        for (int i = 0; i < NACC; ++i) s_red[wid][i] = acc[i];
    }
    __syncthreads();
    if (tid < NACC) {
        const int bid = (blockIdx.z * GY + blockIdx.y) * GX + blockIdx.x;
        partials[(size_t)tid * NBLK + bid] =
            s_red[0][tid] + s_red[1][tid] + s_red[2][tid] + s_red[3][tid];
    }
}

__global__ __launch_bounds__(256) void crack_final(
    const float* __restrict__ partials, float* __restrict__ out)
{
    const int tid = threadIdx.x;
    float a[NACC];
#pragma unroll
    for (int i = 0; i < NACC; ++i) a[i] = 0.f;
    for (int b = tid; b < NBLK; b += 256) {
#pragma unroll
        for (int i = 0; i < NACC; ++i) a[i] += partials[(size_t)i * NBLK + b];
    }
#pragma unroll
    for (int i = 0; i < NACC; ++i) {
        float v = a[i];
#pragma unroll
        for (int off = 32; off; off >>= 1) v += __shfl_xor(v, off);
        a[i] = v;
    }
    __shared__ float s_red[4][NACC];
    const int lane = tid & 63, wid = tid >> 6;
    if (lane == 0) {
#pragma unroll
        for (int i = 0; i < NACC; ++i) s_red[wid][i] = a[i];
    }
    __syncthreads();
    if (tid == 0) {
        float t[NACC];
        for (int i = 0; i < NACC; ++i)
            t[i] = s_red[0][i] + s_red[1][i] + s_red[2][i] + s_red[3][i];
        const float bce   = t[0] / NTOT;
        const float st    = t[2];
        const float sp    = t[1] + t[2];
        const float inter = t[3] + t[2];
        const float dice = 1.f - (2.f * inter + 1.f) / (sp + st + 1.f);
        const float fp = sp - inter, fn = st - inter;
        const float tvi = (inter + 1.f) / (inter + 0.6f * fp + 0.4f * fn + 1.f);
        const float tversky = powf(fmaxf(1.f - tvi, 0.f), 0.75f);
        float tb = 0.f, ns = 0.f;
        for (int i = 0; i < 3; ++i) {
            const float cnt = t[4 + i], sb = t[7 + i];
            if (cnt >= 1.f) { tb += sb / cnt; ns += 1.f; }
        }
        const float boundary = (ns > 0.f) ? tb / ns : 0.f;
        const float detail = t[10] / NTOT;
        out[0] = bce + dice + 0.5f * tversky + 0.5f * boundary + 0.3f * detail;
    }
}

extern "C" void kernel_launch(void* const* d_in, const int* in_sizes, int n_in,
                              void* d_out, int out_size, void* d_ws, size_t ws_size,
                              hipStream_t stream) {
    const float* logits = (const float*)d_in[0];
    const float* target = (const float*)d_in[1];
    float* partials = (float*)d_ws;   // NACC * NBLK floats = 88 KiB, fully overwritten

    dim3 grid(GX, GY, Bn);
    crack_main<<<grid, dim3(256), 0, stream>>>(logits, target, partials);
    crack_final<<<1, 256, 0, stream>>>(partials, (float*)d_out);
}

// Round 9
// 31.251 us; speedup vs baseline: 2.3259x; 1.0961x over previous
//
#include <hip/hip_runtime.h>
#include <math.h>
#include <stdint.h>

constexpr int Hn = 512, Wn = 512, Bn = 16;
constexpr int GX = 2;               // 256-col tiles (4 px/lane)
constexpr int GY = 32;              // 16-row groups (4 waves x 4 rows)
constexpr int NBLK = GX * GY * Bn;  // 1024 blocks
#define NACC 11
constexpr float NTOT = 16.f * 512.f * 512.f;

// partials (transposed [i][blk]): 0 bce, 1 sum_d, 2 sum_t, 3 sum_dt,
//   4..6 cnt(3,5,7), 7..9 bce*mask(3,5,7), 10 detail

__device__ __forceinline__ uint32_t bits4(float4 v) {
    return (uint32_t)(v.x > 0.5f) | ((uint32_t)(v.y > 0.5f) << 1) |
           ((uint32_t)(v.z > 0.5f) << 2) | ((uint32_t)(v.w > 0.5f) << 3);
}
__device__ __forceinline__ float sigm(float x) {
    const float z = __expf(-fabsf(x));
    const float r = __builtin_amdgcn_rcpf(1.f + z);
    return (x >= 0.f) ? r : 1.f - r;
}
__device__ __forceinline__ void pxd(float x, float tf, float& d) {
    const float z = __expf(-fabsf(x));
    const float r = __builtin_amdgcn_rcpf(1.f + z);
    d = ((x >= 0.f) ? r : 1.f - r) - tf;
}
__device__ __forceinline__ void pxb(float x, float tf, float& d, float& b) {
    const float z = __expf(-fabsf(x));
    const float r = __builtin_amdgcn_rcpf(1.f + z);
    d = ((x >= 0.f) ? r : 1.f - r) - tf;
    b = fmaxf((1.f - 2.f * tf) * x, 0.f) + __logf(1.f + z);
}

__global__ __launch_bounds__(256, 4) void crack_main(
    const float* __restrict__ logits, const float* __restrict__ target,
    float* __restrict__ partials)
{
    const int tid  = threadIdx.x;
    const int lane = tid & 63;
    const int wid  = __builtin_amdgcn_readfirstlane(tid >> 6);
    const int x0 = blockIdx.x * 256;
    const int y0 = blockIdx.y * 16 + wid * 4;     // wave owns rows y0..y0+3
    const int cx = x0 + 4 * lane;                 // my 4 columns
    const size_t base = (size_t)blockIdx.z * (size_t)(Hn * Wn);
    const bool leftE  = (x0 == 0);
    const bool rightE = (x0 + 256 >= Wn);

    uint32_t validm = 0xFFFu;                     // erosion-complement validity
    if (leftE  && lane == 0)  validm = 0xFF0u;
    if (rightE && lane == 63) validm = 0x0FFu;

    // ================= issue ALL global loads up front (MLP) =================
    // 10 target rows (y0-3 .. y0+6)
    float4 tf[10];
#pragma unroll
    for (int r = 0; r < 10; ++r) {
        const int gy = y0 - 3 + r;
        tf[r] = make_float4(0.f, 0.f, 0.f, 0.f);
        if ((unsigned)gy < (unsigned)Hn)
            tf[r] = *(const float4*)(target + base + (size_t)gy * Wn + cx);
    }
    // strip-edge target words: lanes 0..9 left (x0-4), lanes 32..41 right (x0+256)
    float4 ef = make_float4(0.f, 0.f, 0.f, 0.f);
    {
        const int q = lane & 31, side = lane >> 5;
        const int gy = y0 - 3 + q;
        if (q < 10 && (unsigned)gy < (unsigned)Hn) {
            if (side == 0 && !leftE)
                ef = *(const float4*)(target + base + (size_t)gy * Wn + (x0 - 4));
            else if (side == 1 && !rightE)
                ef = *(const float4*)(target + base + (size_t)gy * Wn + (x0 + 256));
        }
    }
    // 6 logits rows (y0-1 .. y0+4)
    float4 xf[6];
#pragma unroll
    for (int rr = 0; rr < 6; ++rr) {
        const int gy = y0 - 1 + rr;
        xf[rr] = make_float4(0.f, 0.f, 0.f, 0.f);
        if ((unsigned)gy < (unsigned)Hn)
            xf[rr] = *(const float4*)(logits + base + (size_t)gy * Wn + cx);
    }
    // Laplacian edge columns: lanes 0..3 = rows y0..y0+3 at col x0-1;
    //                         lanes 32..35 = same rows at col x0+256
    float edx = 0.f, edt = 0.f;
    bool edact = false;
    {
        const int q = lane & 31, side = lane >> 5;
        const int gy = y0 + q;
        if (q < 4) {
            if (side == 0 && !leftE) {
                edx = logits[base + (size_t)gy * Wn + (x0 - 1)];
                edt = target[base + (size_t)gy * Wn + (x0 - 1)];
                edact = true;
            } else if (side == 1 && !rightE) {
                edx = logits[base + (size_t)gy * Wn + (x0 + 256)];
                edt = target[base + (size_t)gy * Wn + (x0 + 256)];
                edact = true;
            }
        }
    }

    // ================= convert / cross-lane / cascade =================
    uint32_t mb[10];
#pragma unroll
    for (int r = 0; r < 10; ++r) mb[r] = bits4(tf[r]);
    const uint32_t eb = bits4(ef);
    const float ed = edact ? (sigm(edx) - ((edt > 0.5f) ? 1.f : 0.f)) : 0.f;

    uint32_t po[10], pu[10];
#pragma unroll
    for (int r = 0; r < 10; ++r) {
        const uint32_t m = mb[r];
        uint32_t ml = __shfl_up(m, 1);
        uint32_t mr = __shfl_down(m, 1);
        const uint32_t el = __shfl(eb, r);
        const uint32_t er = __shfl(eb, 32 + r);
        if (lane == 0)  ml = el;
        if (lane == 63) mr = er;
        const uint32_t w = ml | (m << 4) | (mr << 8);   // bit b = col cx-4+b
        const bool rowv = ((unsigned)(y0 - 3 + r) < (unsigned)Hn);
        const uint32_t wc = rowv ? ((~w) & validm) : 0u;
        const uint32_t w1 = w  | (w  << 1) | (w  >> 1);
        const uint32_t w2 = w1 | (w1 << 1) | (w1 >> 1);
        const uint32_t w3 = w2 | (w2 << 1) | (w2 >> 1);
        const uint32_t u1 = wc | (wc << 1) | (wc >> 1);
        const uint32_t u2 = u1 | (u1 << 1) | (u1 >> 1);
        const uint32_t u3 = u2 | (u2 << 1) | (u2 >> 1);
        po[r] = ((w1 >> 4) & 0xFu) | (((w2 >> 4) & 0xFu) << 4) |
                (((w3 >> 4) & 0xFu) << 8);
        pu[r] = ((u1 >> 4) & 0xFu) | (((u2 >> 4) & 0xFu) << 4) |
                (((u3 >> 4) & 0xFu) << 8);
    }

    // ================= phase B: d field + bce + elementwise sums =================
    float4 da[6], b4[6];
    float sbce = 0.f, sd = 0.f, sdt = 0.f, stt = 0.f;
#pragma unroll
    for (int rr = 0; rr < 6; ++rr) {
        const uint32_t m = mb[rr + 2];
        const float t0 = (float)(m & 1u), t1 = (float)((m >> 1) & 1u);
        const float t2 = (float)((m >> 2) & 1u), t3 = (float)((m >> 3) & 1u);
        const float4 x = xf[rr];
        if (rr >= 1 && rr <= 4) {                 // core row
            float4 d, bc;
            pxb(x.x, t0, d.x, bc.x); pxb(x.y, t1, d.y, bc.y);
            pxb(x.z, t2, d.z, bc.z); pxb(x.w, t3, d.w, bc.w);
            da[rr] = d; b4[rr] = bc;
            sbce += bc.x + bc.y + bc.z + bc.w;
            sd   += d.x + d.y + d.z + d.w;
            sdt  += d.x * t0 + d.y * t1 + d.z * t2 + d.w * t3;
            stt  += t0 + t1 + t2 + t3;
        } else {                                  // halo row: d only
            float4 d;
            pxd(x.x, t0, d.x); pxd(x.y, t1, d.y);
            pxd(x.z, t2, d.z); pxd(x.w, t3, d.w);
            // OOB rows: xf==0, t==0 -> d = 0.5; must be 0 for zero-padded conv
            const bool rowv = ((unsigned)(y0 - 1 + rr) < (unsigned)Hn);
            if (!rowv) d = make_float4(0.f, 0.f, 0.f, 0.f);
            da[rr] = d; b4[rr] = make_float4(0.f, 0.f, 0.f, 0.f);
        }
    }

    // ================= phase C: boundary combine + Laplacian =================
    float sb1 = 0.f, sb2 = 0.f, sb3 = 0.f, sdet = 0.f;
    int c1 = 0, c2 = 0, c3 = 0;
#pragma unroll
    for (int k = 0; k < 4; ++k) {                 // core row rr = k+1, center pr = k+3
        const uint32_t o3 = po[k + 2] | po[k + 3] | po[k + 4];
        const uint32_t o5 = o3 | po[k + 1] | po[k + 5];
        const uint32_t o7 = o5 | po[k] | po[k + 6];
        const uint32_t p3 = pu[k + 2] | pu[k + 3] | pu[k + 4];
        const uint32_t p5 = p3 | pu[k + 1] | pu[k + 5];
        const uint32_t p7 = p5 | pu[k] | pu[k + 6];
        const uint32_t vo = (o3 & 0xFu) | (o5 & 0xF0u) | (o7 & 0xF00u);
        const uint32_t vu = (p3 & 0xFu) | (p5 & 0xF0u) | (p7 & 0xF00u);
        const uint32_t b = vo & vu;               // [0:4) r1, [4:8) r2, [8:12) r3
        c1 += __popc(b & 0xFu);
        c2 += __popc(b & 0xF0u);
        c3 += __popc(b & 0xF00u);
        const float4 bc = b4[k + 1];
        sb1 += (((b >> 0) & 1) ? bc.x : 0.f) + (((b >> 1) & 1) ? bc.y : 0.f) +
               (((b >> 2) & 1) ? bc.z : 0.f) + (((b >> 3) & 1) ? bc.w : 0.f);
        sb2 += (((b >> 4) & 1) ? bc.x : 0.f) + (((b >> 5) & 1) ? bc.y : 0.f) +
               (((b >> 6) & 1) ? bc.z : 0.f) + (((b >> 7) & 1) ? bc.w : 0.f);
        sb3 += (((b >> 8) & 1) ? bc.x : 0.f) + (((b >> 9) & 1) ? bc.y : 0.f) +
               (((b >> 10) & 1) ? bc.z : 0.f) + (((b >> 11) & 1) ? bc.w : 0.f);

        const float4 ce = da[k + 1];
        const float4 up = da[k];
        const float4 dn = da[k + 2];
        float left = __shfl_up(ce.w, 1);
        { const float el = __shfl(ed, k); if (lane == 0)  left = el; }
        float right = __shfl_down(ce.x, 1);
        { const float er = __shfl(ed, 32 + k); if (lane == 63) right = er; }
        sdet += fabsf(left + ce.y + up.x + dn.x - 4.f * ce.x);
        sdet += fabsf(ce.x + ce.z + up.y + dn.y - 4.f * ce.y);
        sdet += fabsf(ce.y + ce.w + up.z + dn.z - 4.f * ce.z);
        sdet += fabsf(ce.z + right + up.w + dn.w - 4.f * ce.w);
    }

    // ================= block reduction -> partials (no atomics) =================
    float acc[NACC];
    acc[0] = sbce; acc[1] = sd; acc[2] = stt; acc[3] = sdt;
    acc[4] = (float)c1; acc[5] = (float)c2; acc[6] = (float)c3;
    acc[7] = sb1; acc[8] = sb2; acc[9] = sb3; acc[10] = sdet;
#pragma unroll
    for (int i = 0; i < NACC; ++i) {
        float v = acc[i];
#pragma unroll
        for (int off = 32; off; off >>= 1) v += __shfl_xor(v, off);
        acc[i] = v;
    }
    __shared__ float s_red[4][NACC];
    if (lane == 0) {
#pragma unroll
        for (int i = 0; i < NACC; ++i) s_red[wid][i] = acc[i];
    }
    __syncthreads();
    if (tid < NACC) {
        const int bid = (blockIdx.z * GY + blockIdx.y) * GX + blockIdx.x;
        partials[(size_t)tid * NBLK + bid] =
            s_red[0][tid] + s_red[1][tid] + s_red[2][tid] + s_red[3][tid];
    }
}

__global__ __launch_bounds__(1024) void crack_final(
    const float* __restrict__ partials, float* __restrict__ out)
{
    const int tid = threadIdx.x;                  // 1024 threads == NBLK
    float a[NACC];
#pragma unroll
    for (int i = 0; i < NACC; ++i) a[i] = partials[(size_t)i * NBLK + tid];
#pragma unroll
    for (int i = 0; i < NACC; ++i) {
        float v = a[i];
#pragma unroll
        for (int off = 32; off; off >>= 1) v += __shfl_xor(v, off);
        a[i] = v;
    }
    __shared__ float s_red[16][NACC];
    const int lane = tid & 63, wid = tid >> 6;
    if (lane == 0) {
#pragma unroll
        for (int i = 0; i < NACC; ++i) s_red[wid][i] = a[i];
    }
    __syncthreads();
    if (tid == 0) {
        float t[NACC];
        for (int i = 0; i < NACC; ++i) {
            float v = 0.f;
            for (int w = 0; w < 16; ++w) v += s_red[w][i];
            t[i] = v;
        }
        const float bce   = t[0] / NTOT;
        const float st    = t[2];
        const float sp    = t[1] + t[2];
        const float inter = t[3] + t[2];
        const float dice = 1.f - (2.f * inter + 1.f) / (sp + st + 1.f);
        const float fp = sp - inter, fn = st - inter;
        const float tvi = (inter + 1.f) / (inter + 0.6f * fp + 0.4f * fn + 1.f);
        const float tversky = powf(fmaxf(1.f - tvi, 0.f), 0.75f);
        float tb = 0.f, ns = 0.f;
        for (int i = 0; i < 3; ++i) {
            const float cnt = t[4 + i], sb = t[7 + i];
            if (cnt >= 1.f) { tb += sb / cnt; ns += 1.f; }
        }
        const float boundary = (ns > 0.f) ? tb / ns : 0.f;
        const float detail = t[10] / NTOT;
        out[0] = bce + dice + 0.5f * tversky + 0.5f * boundary + 0.3f * detail;
    }
}

extern "C" void kernel_launch(void* const* d_in, const int* in_sizes, int n_in,
                              void* d_out, int out_size, void* d_ws, size_t ws_size,
                              hipStream_t stream) {
    const float* logits = (const float*)d_in[0];
    const float* target = (const float*)d_in[1];
    float* partials = (float*)d_ws;   // NACC * NBLK floats = 45 KiB, fully overwritten

    dim3 grid(GX, GY, Bn);
    crack_main<<<grid, dim3(256), 0, stream>>>(logits, target, partials);
    crack_final<<<1, 1024, 0, stream>>>(partials, (float*)d_out);
}